// Round 16
// baseline (346.727 us; speedup 1.0000x reference)
//
#include <hip/hip_runtime.h>
#include <hip/hip_bf16.h>
#include <math.h>

#define NN 16384
#define DEG 20
#define EE (NN*DEG)
#define RMAXF 3.5f
#define NGRP 5   // groups of 16 edges per block (80 edges = 4 nodes)

typedef __attribute__((ext_vector_type(8))) short short8;
typedef __attribute__((ext_vector_type(4))) float f32x4;

// soft_unit_step: exp(-1/x) for x>0 else 0
__device__ __forceinline__ float su_f(float x) {
    return x > 0.0f ? __expf(-1.0f / x) : 0.0f;
}
__device__ __forceinline__ ushort f2bf(float x) {
    __hip_bfloat16 h = __float2bfloat16(x);
    return *reinterpret_cast<ushort*>(&h);
}

// ---------------------------------------------------------------------------
// edge_kernel (single launch): block = 256 threads = 4 waves; owns 4 whole
// nodes (80 edges, 5 groups of 16). Round-12 arithmetic VERBATIM; barrier
// restructure only:
//  - phase A wave-localized: wave w's lanes 0-31 stage s_g rows 4w..4w+3,
//    lanes 32-35 compute geometry/basis for those rows. All rows of
//    s_emb/s_s1/s_g consumed by wave w in phases B/D are its own 4 rows,
//    so the A->B barrier is unnecessary (wave-internal LDS ordering).
//  - barrier 4 (D -> next group's A) removed: the only cross-wave hazards,
//    D(g) reads s_w vs C(g+1) writes (fenced by barrier 2 of g+1) and
//    C(g) reads s_hb vs B(g+1) writes (fenced by barrier 3 of g), are
//    already covered; s_g/s_s1/s_emb rewrites are same-wave program-order.
//  => 2 barriers/group + 1 pre-epilogue = 11 vs round-12's 20.
// Relies on edst[e] == e/20 (contiguous segments; exploited since round 1).
// ---------------------------------------------------------------------------
__global__ __launch_bounds__(256, 3) void edge_kernel(
    const float* __restrict__ f,   const float* __restrict__ pos,
    const float* __restrict__ Wqs, const float* __restrict__ Wqv,
    const float* __restrict__ Wds, const float* __restrict__ Wdv,
    const float* __restrict__ Wk1, const float* __restrict__ Wv1,
    const float* __restrict__ Wk2, const float* __restrict__ Wv2,
    const int* __restrict__ esrc,  float* __restrict__ out)
{
    __shared__ float  s_w[2][16][261];                // 33.4 KB, D matrices (k,v)
    __shared__ __align__(16) ushort s_hb[2][16][64];  // 4 KB bf16 h, XOR-swizzled
    __shared__ __align__(16) float s_g[16][36];       // 2.25 KB, f[src], pad 36
    __shared__ float s_emb[16][10];
    __shared__ float s_s1[16][4];
    __shared__ float s_v[80][33];                     // 10.6 KB, per-edge v
    __shared__ float s_lg[80];                        // per-edge logits
    __shared__ float s_cut[80];                       // per-edge cutoff
    __shared__ float s_mqn[4][32];                    // mq for block's 4 nodes

    const int t = threadIdx.x;
    const int wave = t >> 6, lane = t & 63;
    const int qd = lane >> 4, n = lane & 15;
    const int n0 = blockIdx.x * 4;                    // first node of block
    const int E0 = n0 * DEG;                          // first edge of block

    // ---- prologue A: mq for the block's 4 dst nodes (verbatim prep math).
    //      Read in phase D, which is always >= 2 barriers downstream. ----
    if (t < 128) {
        int nd = t >> 5, idx = t & 31;
        const float* fr = f + (size_t)(n0 + nd) * 32;
        const float inv8 = 0.35355339059327373f; // 1/sqrt(8)
        float o_ = 0.0f;
        if (idx < 8) {
            int j = idx;
            #pragma unroll
            for (int i = 0; i < 8; i++) {
                float qs = 0.0f;
                #pragma unroll
                for (int a = 0; a < 8; a++) qs = fmaf(fr[a], Wqs[a * 8 + i], qs);
                o_ = fmaf(qs * inv8, Wds[i * 8 + j], o_);
            }
        } else {
            int kk = idx - 8;
            int j = kk / 3, c = kk - 3 * j;
            #pragma unroll
            for (int i = 0; i < 8; i++) {
                float qv = 0.0f;
                #pragma unroll
                for (int a = 0; a < 8; a++) qv = fmaf(fr[8 + 3 * a + c], Wqv[a * 8 + i], qv);
                o_ = fmaf(qv * inv8, Wdv[i * 8 + j], o_);
            }
            o_ *= 0.5773502691896258f; // 1/sqrt(3)
        }
        s_mqn[nd][idx] = o_;
    }

    // ---- prologue B: W1 rows for this lane (20 regs) ----
    float wk1r[10], wv1r[10];
    #pragma unroll
    for (int j = 0; j < 10; j++) {
        wk1r[j] = Wk1[j * 64 + lane];
        wv1r[j] = Wv1[j * 64 + lane];
    }

    // ---- prologue C: B fragments packed directly from W2 (both nets) ----
    // breg[net][s][jj] = 8 bf16: W2[k=s*32+qd*8+j][col=(wave*4+jj)*16+n]*0.125
    short8 breg[2][2][4];
    #pragma unroll
    for (int net = 0; net < 2; net++) {
        const float* W2 = net ? Wv2 : Wk2;
        #pragma unroll
        for (int s = 0; s < 2; s++)
            #pragma unroll
            for (int jj = 0; jj < 4; jj++) {
                int col = (wave * 4 + jj) * 16 + n;
                union { ushort u[8]; short8 v; } bf;
                #pragma unroll
                for (int j = 0; j < 8; j++) {
                    int k0 = s * 32 + qd * 8 + j;
                    bf.u[j] = f2bf(W2[k0 * 256 + col] * 0.125f);
                }
                breg[net][s][jj] = bf.v;
            }
    }

    for (int g = 0; g < NGRP; g++) {
        const int le0 = g * 16;            // local edge base
        const int e0 = E0 + le0;

        // ---- phase A (wave-local, NO barrier after): each wave handles its
        //      own 4 rows. Lanes 0-31: stage s_g; lanes 32-35: geometry. ----
        if (lane < 32) {
            int el = wave * 4 + (lane >> 3), c4 = lane & 7;
            int s = esrc[e0 + el];
            float4 x = *reinterpret_cast<const float4*>(f + (size_t)s * 32 + c4 * 4);
            *reinterpret_cast<float4*>(&s_g[el][c4 * 4]) = x;
        } else if (lane < 36) {
            int el = wave * 4 + (lane - 32);
            int e = e0 + el;
            int s = esrc[e];
            int d = n0 + (le0 + el) / DEG;  // edst[e] == e/20
            float vx = pos[s * 3 + 0] - pos[d * 3 + 0];
            float vy = pos[s * 3 + 1] - pos[d * 3 + 1];
            float vz = pos[s * 3 + 2] - pos[d * 3 + 2];
            float r = sqrtf(vx * vx + vy * vy + vz * vz);
            float invr = 1.0f / r;
            const float sqrt3 = 1.7320508075688772f;
            s_s1[el][0] = sqrt3 * vx * invr;
            s_s1[el][1] = sqrt3 * vy * invr;
            s_s1[el][2] = sqrt3 * vz * invr;
            s_cut[le0 + el] = su_f(10.0f * (1.0f - r / RMAXF));
            const float step = RMAXF / 11.0f;
            const float invstep = 11.0f / RMAXF;
            const float K = 26.66929988626f; // 1.14136*e^2*sqrt(10)
            #pragma unroll
            for (int j = 0; j < 10; j++) {
                float dd = (r - step * (float)(j + 1)) * invstep;
                s_emb[el][j] = K * su_f(dd + 1.0f) * su_f(1.0f - dd);
            }
        }
        // (no __syncthreads: phases B/D of wave w read only rows 4w..4w+3,
        //  written above by wave w itself; wave-internal lgkmcnt orders them)

        // ---- phase B: GEMM1 (W1 in regs) + silu (both nets) -> s_hb ----
        {
            const float invsq10 = 0.31622776601683794f; // 1/sqrt(10)
            #pragma unroll
            for (int e = 0; e < 4; e++) {
                int el = wave * 4 + e;
                float ak = 0.0f, av = 0.0f;
                #pragma unroll
                for (int j = 0; j < 10; j++) {
                    float ej = s_emb[el][j];
                    ak = fmaf(ej, wk1r[j], ak);
                    av = fmaf(ej, wv1r[j], av);
                }
                ak *= invsq10; av *= invsq10;
                float hk = ak / (1.0f + __expf(-ak));
                float hv = av / (1.0f + __expf(-av));
                int pos_ = ((((lane >> 3) ^ (el & 7))) << 3) | (lane & 7);
                s_hb[0][el][pos_] = f2bf(hk);
                s_hb[1][el][pos_] = f2bf(hv);
            }
        }
        __syncthreads(); // barrier 2: s_hb cross-wave (C reads all rows);
                         // also fences D(g-1)'s s_w reads vs C(g)'s writes

        // ---- phase C: MFMA GEMM2 for both nets -> s_w[net] (proven layout) ----
        #pragma unroll
        for (int net = 0; net < 2; net++) {
            short8 ha0 = *(const short8*)&s_hb[net][n][((qd ^ (n & 7)) << 3)];
            short8 ha1 = *(const short8*)&s_hb[net][n][(((4 + qd) ^ (n & 7)) << 3)];
            #pragma unroll
            for (int jj = 0; jj < 4; jj++) {
                int tt = wave * 4 + jj;
                f32x4 d = {0.0f, 0.0f, 0.0f, 0.0f};
                d = __builtin_amdgcn_mfma_f32_16x16x32_bf16(ha0, breg[net][0][jj], d, 0, 0, 0);
                d = __builtin_amdgcn_mfma_f32_16x16x32_bf16(ha1, breg[net][1][jj], d, 0, 0, 0);
                #pragma unroll
                for (int r = 0; r < 4; r++)
                    s_w[net][4 * qd + r][tt * 16 + n] = d[r]; // D: row=4*quad+reg, col=n
            }
        }
        __syncthreads(); // barrier 3: s_w cross-wave (D reads all cols);
                         // also fences C(g)'s s_hb reads vs B(g+1)'s writes

        // ---- phase D: round-12 verbatim. el = t>>4 -> own wave's rows. ----
        {
            int el = t >> 4, role = t & 15;
            int le = le0 + el;
            int nd = le / DEG;             // local dst node of this edge
            float s1x = s_s1[el][0], s1y = s_s1[el][1], s1z = s_s1[el][2];
            const float inv_sqrt3 = 0.5773502691896258f;
            float gg[32];
            #pragma unroll
            for (int v4 = 0; v4 < 8; v4++) {
                float4 x = *reinterpret_cast<const float4*>(&s_g[el][v4 * 4]);
                gg[v4 * 4 + 0] = x.x; gg[v4 * 4 + 1] = x.y;
                gg[v4 * 4 + 2] = x.z; gg[v4 * 4 + 3] = x.w;
            }
            float a[8], b[8];
            #pragma unroll
            for (int i = 0; i < 8; i++) {
                a[i] = gg[i];
                b[i] = (gg[8 + i * 3 + 0] * s1x +
                        gg[8 + i * 3 + 1] * s1y +
                        gg[8 + i * 3 + 2] * s1z) * inv_sqrt3;
            }
            const float nrm = 0.25f; // 1/(sqrt(8)*sqrt(2))
            const float* wk = s_w[0][el];
            const float* wv = s_w[1][el];
            float contrib = 0.0f;
            if (role < 8) {
                int o = role;
                float ks = 0.0f, vs = 0.0f;
                #pragma unroll
                for (int i = 0; i < 8; i++) {
                    ks += a[i] * wk[i * 8 + o] + b[i] * wk[64 + i * 8 + o];
                    vs += a[i] * wv[i * 8 + o] + b[i] * wv[64 + i * 8 + o];
                }
                contrib = s_mqn[nd][o] * (ks * nrm);
                s_v[le][o] = vs * nrm;
            } else {
                int o = role - 8;
                #pragma unroll
                for (int c = 0; c < 3; c++) {
                    float uk = 0.0f, tk = 0.0f, uv = 0.0f, tv = 0.0f;
                    #pragma unroll
                    for (int i = 0; i < 8; i++) {
                        uk += a[i] * wk[128 + i * 8 + o];
                        tk = fmaf(gg[8 + i * 3 + c], wk[192 + i * 8 + o], tk);
                        uv += a[i] * wv[128 + i * 8 + o];
                        tv = fmaf(gg[8 + i * 3 + c], wv[192 + i * 8 + o], tv);
                    }
                    float kv_c = nrm * (s_s1[el][c] * uk + tk);
                    contrib = fmaf(s_mqn[nd][8 + 3 * o + c], kv_c, contrib);
                    s_v[le][8 + o * 3 + c] = nrm * (s_s1[el][c] * uv + tv);
                }
            }
            contrib += __shfl_xor(contrib, 1);
            contrib += __shfl_xor(contrib, 2);
            contrib += __shfl_xor(contrib, 4);
            contrib += __shfl_xor(contrib, 8);
            if (role == 0) s_lg[le] = contrib * 0.08838834764831845f; // 1/(8*sqrt2)
        }
        // (no barrier 4: next group's A writes are same-wave rows; s_w/s_hb
        //  hazards are fenced by barriers 2 and 3 of the next iteration)
    }
    __syncthreads(); // final: s_v/s_lg/s_cut ready for epilogue

    // ---- epilogue: per-node softmax + weighted sum (proven out_kernel math).
    //      wave w handles node n0+w; both 32-lane halves compute identically.
    {
        int base_le = DEG * wave;
        int h32 = lane & 32;
        int hl = lane & 31;
        float lg = -INFINITY, cw = 0.0f;
        if (hl < DEG) {
            lg = s_lg[base_le + hl];
            cw = s_cut[base_le + hl];
        }
        float mx = lg;
        mx = fmaxf(mx, __shfl_xor(mx, 16));
        mx = fmaxf(mx, __shfl_xor(mx, 8));
        mx = fmaxf(mx, __shfl_xor(mx, 4));
        mx = fmaxf(mx, __shfl_xor(mx, 2));
        mx = fmaxf(mx, __shfl_xor(mx, 1));

        float ew = cw * __expf(lg - mx);
        float z = ew;
        z += __shfl_xor(z, 16);
        z += __shfl_xor(z, 8);
        z += __shfl_xor(z, 4);
        z += __shfl_xor(z, 2);
        z += __shfl_xor(z, 1);
        z = (z == 0.0f) ? 1.0f : z;
        float coef = sqrtf(ew / z + 1e-12f);

        float acc = 0.0f;
        #pragma unroll
        for (int ee = 0; ee < DEG; ee++) {
            float ce = __shfl(coef, h32 + ee);
            acc = fmaf(ce, s_v[base_le + ee][hl], acc);
        }
        if (lane < 32) out[(size_t)(n0 + wave) * 32 + hl] = acc;
    }
}

// ---------------------------------------------------------------------------
extern "C" void kernel_launch(void* const* d_in, const int* in_sizes, int n_in,
                              void* d_out, int out_size, void* d_ws, size_t ws_size,
                              hipStream_t stream) {
    const float* f    = (const float*)d_in[0];
    const float* pos  = (const float*)d_in[1];
    const float* Wqs  = (const float*)d_in[2];
    const float* Wqv  = (const float*)d_in[3];
    const float* Wk1  = (const float*)d_in[4];
    const float* Wk2  = (const float*)d_in[5];
    const float* Wv1  = (const float*)d_in[6];
    const float* Wv2  = (const float*)d_in[7];
    const float* Wds  = (const float*)d_in[8];
    const float* Wdv  = (const float*)d_in[9];
    const int* esrc   = (const int*)d_in[10];
    float* out        = (float*)d_out;

    edge_kernel<<<dim3(NN / 4), dim3(256), 0, stream>>>(
        f, pos, Wqs, Wqv, Wds, Wdv, Wk1, Wv1, Wk2, Wv2, esrc, out);
}

// Round 17
// 249.579 us; speedup vs baseline: 1.3892x; 1.3892x over previous
//
#include <hip/hip_runtime.h>
#include <hip/hip_bf16.h>
#include <math.h>

#define NN 16384
#define DEG 20
#define EE (NN*DEG)
#define RMAXF 3.5f
#define NGRP 5   // groups of 16 edges per block (80 edges = 4 nodes)

typedef __attribute__((ext_vector_type(8))) short short8;
typedef __attribute__((ext_vector_type(4))) float f32x4;

// soft_unit_step: exp(-1/x) for x>0 else 0
__device__ __forceinline__ float su_f(float x) {
    return x > 0.0f ? __expf(-1.0f / x) : 0.0f;
}
__device__ __forceinline__ ushort f2bf(float x) {
    __hip_bfloat16 h = __float2bfloat16(x);
    return *reinterpret_cast<ushort*>(&h);
}

// ---------------------------------------------------------------------------
// edge_kernel (single launch): block = 256 threads = 4 waves; owns 4 whole
// nodes (80 edges, 5 groups of 16). EXACT round-12 structure (the proven
// allocator-stable 244 us configuration: 4 barriers/group, divergent
// lane-role phase D, (256,3) bound) with ONE strictly pressure-reducing
// change: phase D uses round-11's direct scalar s_g reads instead of the
// gg[32] float4 staging array (round 11's edge kernel measured 182 vs
// round 12's 186 us; the staging array is the only phase-D difference).
// Relies on edst[e] == e/20 (contiguous segments; exploited since round 1).
// ---------------------------------------------------------------------------
__global__ __launch_bounds__(256, 3) void edge_kernel(
    const float* __restrict__ f,   const float* __restrict__ pos,
    const float* __restrict__ Wqs, const float* __restrict__ Wqv,
    const float* __restrict__ Wds, const float* __restrict__ Wdv,
    const float* __restrict__ Wk1, const float* __restrict__ Wv1,
    const float* __restrict__ Wk2, const float* __restrict__ Wv2,
    const int* __restrict__ esrc,  float* __restrict__ out)
{
    __shared__ float  s_w[2][16][261];                // 33.4 KB, D matrices (k,v)
    __shared__ __align__(16) ushort s_hb[2][16][64];  // 4 KB bf16 h, XOR-swizzled
    __shared__ __align__(16) float s_g[16][36];       // 2.25 KB, f[src], pad 36
    __shared__ float s_emb[16][10];
    __shared__ float s_s1[16][4];
    __shared__ float s_v[80][33];                     // 10.6 KB, per-edge v
    __shared__ float s_lg[80];                        // per-edge logits
    __shared__ float s_cut[80];                       // per-edge cutoff
    __shared__ float s_mqn[4][32];                    // mq for block's 4 nodes

    const int t = threadIdx.x;
    const int wave = t >> 6, lane = t & 63;
    const int qd = lane >> 4, n = lane & 15;
    const int n0 = blockIdx.x * 4;                    // first node of block
    const int E0 = n0 * DEG;                          // first edge of block

    // ---- prologue A: mq for the block's 4 dst nodes (verbatim prep math) ----
    if (t < 128) {
        int nd = t >> 5, idx = t & 31;
        const float* fr = f + (size_t)(n0 + nd) * 32;
        const float inv8 = 0.35355339059327373f; // 1/sqrt(8)
        float o_ = 0.0f;
        if (idx < 8) {
            int j = idx;
            #pragma unroll
            for (int i = 0; i < 8; i++) {
                float qs = 0.0f;
                #pragma unroll
                for (int a = 0; a < 8; a++) qs = fmaf(fr[a], Wqs[a * 8 + i], qs);
                o_ = fmaf(qs * inv8, Wds[i * 8 + j], o_);
            }
        } else {
            int kk = idx - 8;
            int j = kk / 3, c = kk - 3 * j;
            #pragma unroll
            for (int i = 0; i < 8; i++) {
                float qv = 0.0f;
                #pragma unroll
                for (int a = 0; a < 8; a++) qv = fmaf(fr[8 + 3 * a + c], Wqv[a * 8 + i], qv);
                o_ = fmaf(qv * inv8, Wdv[i * 8 + j], o_);
            }
            o_ *= 0.5773502691896258f; // 1/sqrt(3)
        }
        s_mqn[nd][idx] = o_;
    }

    // ---- prologue B: W1 rows for this lane (20 regs) ----
    float wk1r[10], wv1r[10];
    #pragma unroll
    for (int j = 0; j < 10; j++) {
        wk1r[j] = Wk1[j * 64 + lane];
        wv1r[j] = Wv1[j * 64 + lane];
    }

    // ---- prologue C: B fragments packed directly from W2 (both nets) ----
    // breg[net][s][jj] = 8 bf16: W2[k=s*32+qd*8+j][col=(wave*4+jj)*16+n]*0.125
    short8 breg[2][2][4];
    #pragma unroll
    for (int net = 0; net < 2; net++) {
        const float* W2 = net ? Wv2 : Wk2;
        #pragma unroll
        for (int s = 0; s < 2; s++)
            #pragma unroll
            for (int jj = 0; jj < 4; jj++) {
                int col = (wave * 4 + jj) * 16 + n;
                union { ushort u[8]; short8 v; } bf;
                #pragma unroll
                for (int j = 0; j < 8; j++) {
                    int k0 = s * 32 + qd * 8 + j;
                    bf.u[j] = f2bf(W2[k0 * 256 + col] * 0.125f);
                }
                breg[net][s][jj] = bf.v;
            }
    }

    for (int g = 0; g < NGRP; g++) {
        const int le0 = g * 16;            // local edge base
        const int e0 = E0 + le0;

        // ---- phase A: geometry + radial basis (threads 0..15) ----
        if (t < 16) {
            int e = e0 + t;
            int s = esrc[e];
            int d = n0 + (le0 + t) / DEG;  // edst[e] == e/20
            float vx = pos[s * 3 + 0] - pos[d * 3 + 0];
            float vy = pos[s * 3 + 1] - pos[d * 3 + 1];
            float vz = pos[s * 3 + 2] - pos[d * 3 + 2];
            float r = sqrtf(vx * vx + vy * vy + vz * vz);
            float invr = 1.0f / r;
            const float sqrt3 = 1.7320508075688772f;
            s_s1[t][0] = sqrt3 * vx * invr;
            s_s1[t][1] = sqrt3 * vy * invr;
            s_s1[t][2] = sqrt3 * vz * invr;
            s_cut[le0 + t] = su_f(10.0f * (1.0f - r / RMAXF));
            const float step = RMAXF / 11.0f;
            const float invstep = 11.0f / RMAXF;
            const float K = 26.66929988626f; // 1.14136*e^2*sqrt(10)
            #pragma unroll
            for (int j = 0; j < 10; j++) {
                float dd = (r - step * (float)(j + 1)) * invstep;
                s_emb[t][j] = K * su_f(dd + 1.0f) * su_f(1.0f - dd);
            }
        }
        // ---- phase A2: stage gathered f[src] rows (float4, threads 0..127) ----
        if (t < 128) {
            int el = t >> 3, c4 = t & 7;
            int s = esrc[e0 + el];
            float4 x = *reinterpret_cast<const float4*>(f + (size_t)s * 32 + c4 * 4);
            *reinterpret_cast<float4*>(&s_g[el][c4 * 4]) = x;
        }
        __syncthreads(); // barrier 1

        // ---- phase B: GEMM1 (W1 in regs) + silu (both nets) -> s_hb ----
        {
            const float invsq10 = 0.31622776601683794f; // 1/sqrt(10)
            #pragma unroll
            for (int e = 0; e < 4; e++) {
                int el = wave * 4 + e;
                float ak = 0.0f, av = 0.0f;
                #pragma unroll
                for (int j = 0; j < 10; j++) {
                    float ej = s_emb[el][j];
                    ak = fmaf(ej, wk1r[j], ak);
                    av = fmaf(ej, wv1r[j], av);
                }
                ak *= invsq10; av *= invsq10;
                float hk = ak / (1.0f + __expf(-ak));
                float hv = av / (1.0f + __expf(-av));
                int pos_ = ((((lane >> 3) ^ (el & 7))) << 3) | (lane & 7);
                s_hb[0][el][pos_] = f2bf(hk);
                s_hb[1][el][pos_] = f2bf(hv);
            }
        }
        __syncthreads(); // barrier 2

        // ---- phase C: MFMA GEMM2 for both nets -> s_w[net] (proven layout) ----
        #pragma unroll
        for (int net = 0; net < 2; net++) {
            short8 ha0 = *(const short8*)&s_hb[net][n][((qd ^ (n & 7)) << 3)];
            short8 ha1 = *(const short8*)&s_hb[net][n][(((4 + qd) ^ (n & 7)) << 3)];
            #pragma unroll
            for (int jj = 0; jj < 4; jj++) {
                int tt = wave * 4 + jj;
                f32x4 d = {0.0f, 0.0f, 0.0f, 0.0f};
                d = __builtin_amdgcn_mfma_f32_16x16x32_bf16(ha0, breg[net][0][jj], d, 0, 0, 0);
                d = __builtin_amdgcn_mfma_f32_16x16x32_bf16(ha1, breg[net][1][jj], d, 0, 0, 0);
                #pragma unroll
                for (int r = 0; r < 4; r++)
                    s_w[net][4 * qd + r][tt * 16 + n] = d[r]; // D: row=4*quad+reg, col=n
            }
        }
        __syncthreads(); // barrier 3

        // ---- phase D: round-11 proven body (direct s_g reads, no staging) ----
        {
            int el = t >> 4, role = t & 15;
            int le = le0 + el;
            int nd = le / DEG;             // local dst node of this edge
            float s1x = s_s1[el][0], s1y = s_s1[el][1], s1z = s_s1[el][2];
            const float inv_sqrt3 = 0.5773502691896258f;
            float a[8], b[8];
            #pragma unroll
            for (int i = 0; i < 8; i++) {
                a[i] = s_g[el][i];
                b[i] = (s_g[el][8 + i * 3 + 0] * s1x +
                        s_g[el][8 + i * 3 + 1] * s1y +
                        s_g[el][8 + i * 3 + 2] * s1z) * inv_sqrt3;
            }
            const float nrm = 0.25f; // 1/(sqrt(8)*sqrt(2))

            // --- k-net: this role's ks/kv contracted with mq ---
            const float* wk = s_w[0][el];
            float contrib = 0.0f;
            if (role < 8) {
                int o = role;
                float ks = 0.0f;
                #pragma unroll
                for (int i = 0; i < 8; i++)
                    ks += a[i] * wk[i * 8 + o] + b[i] * wk[64 + i * 8 + o];
                contrib = s_mqn[nd][o] * (ks * nrm);
            } else {
                int o = role - 8;
                #pragma unroll
                for (int c = 0; c < 3; c++) {
                    float uk = 0.0f, tk = 0.0f;
                    #pragma unroll
                    for (int i = 0; i < 8; i++) {
                        uk += a[i] * wk[128 + i * 8 + o];
                        tk = fmaf(s_g[el][8 + i * 3 + c], wk[192 + i * 8 + o], tk);
                    }
                    float kv_c = nrm * (s_s1[el][c] * uk + tk);
                    contrib = fmaf(s_mqn[nd][8 + 3 * o + c], kv_c, contrib);
                }
            }
            contrib += __shfl_xor(contrib, 1);
            contrib += __shfl_xor(contrib, 2);
            contrib += __shfl_xor(contrib, 4);
            contrib += __shfl_xor(contrib, 8);
            if (role == 0) s_lg[le] = contrib * 0.08838834764831845f; // 1/(8*sqrt2)

            // --- v-net TP -> s_v ---
            const float* wv = s_w[1][el];
            if (role < 8) {
                int o = role;
                float vs = 0.0f;
                #pragma unroll
                for (int i = 0; i < 8; i++)
                    vs += a[i] * wv[i * 8 + o] + b[i] * wv[64 + i * 8 + o];
                s_v[le][o] = vs * nrm;
            } else {
                int o = role - 8;
                #pragma unroll
                for (int c = 0; c < 3; c++) {
                    float uv = 0.0f, tv = 0.0f;
                    #pragma unroll
                    for (int i = 0; i < 8; i++) {
                        uv += a[i] * wv[128 + i * 8 + o];
                        tv = fmaf(s_g[el][8 + i * 3 + c], wv[192 + i * 8 + o], tv);
                    }
                    s_v[le][8 + o * 3 + c] = nrm * (s_s1[el][c] * uv + tv);
                }
            }
        }
        __syncthreads(); // barrier 4: protects s_* for next group / epilogue
    }

    // ---- epilogue: per-node softmax + weighted sum (proven out_kernel math).
    //      wave w handles node n0+w; both 32-lane halves compute identically.
    {
        int base_le = DEG * wave;
        int h32 = lane & 32;
        int hl = lane & 31;
        float lg = -INFINITY, cw = 0.0f;
        if (hl < DEG) {
            lg = s_lg[base_le + hl];
            cw = s_cut[base_le + hl];
        }
        float mx = lg;
        mx = fmaxf(mx, __shfl_xor(mx, 16));
        mx = fmaxf(mx, __shfl_xor(mx, 8));
        mx = fmaxf(mx, __shfl_xor(mx, 4));
        mx = fmaxf(mx, __shfl_xor(mx, 2));
        mx = fmaxf(mx, __shfl_xor(mx, 1));

        float ew = cw * __expf(lg - mx);
        float z = ew;
        z += __shfl_xor(z, 16);
        z += __shfl_xor(z, 8);
        z += __shfl_xor(z, 4);
        z += __shfl_xor(z, 2);
        z += __shfl_xor(z, 1);
        z = (z == 0.0f) ? 1.0f : z;
        float coef = sqrtf(ew / z + 1e-12f);

        float acc = 0.0f;
        #pragma unroll
        for (int ee = 0; ee < DEG; ee++) {
            float ce = __shfl(coef, h32 + ee);
            acc = fmaf(ce, s_v[base_le + ee][hl], acc);
        }
        if (lane < 32) out[(size_t)(n0 + wave) * 32 + hl] = acc;
    }
}

// ---------------------------------------------------------------------------
extern "C" void kernel_launch(void* const* d_in, const int* in_sizes, int n_in,
                              void* d_out, int out_size, void* d_ws, size_t ws_size,
                              hipStream_t stream) {
    const float* f    = (const float*)d_in[0];
    const float* pos  = (const float*)d_in[1];
    const float* Wqs  = (const float*)d_in[2];
    const float* Wqv  = (const float*)d_in[3];
    const float* Wk1  = (const float*)d_in[4];
    const float* Wk2  = (const float*)d_in[5];
    const float* Wv1  = (const float*)d_in[6];
    const float* Wv2  = (const float*)d_in[7];
    const float* Wds  = (const float*)d_in[8];
    const float* Wdv  = (const float*)d_in[9];
    const int* esrc   = (const int*)d_in[10];
    float* out        = (float*)d_out;

    edge_kernel<<<dim3(NN / 4), dim3(256), 0, stream>>>(
        f, pos, Wqs, Wqv, Wds, Wdv, Wk1, Wv1, Wk2, Wv2, esrc, out);
}